// Round 1
// 728.631 us; speedup vs baseline: 1.5209x; 1.5209x over previous
//
#include <hip/hip_runtime.h>

// Problem constants
static constexpr int SEQ = 50;
static constexpr int DIM = 32;

// ---------------------------------------------------------------------------
// Load one 32-float row (8x float4, coalesced across lanes = consecutive rows)
__device__ __forceinline__ void load_row(const float* __restrict__ p, float x[DIM]) {
    #pragma unroll
    for (int c = 0; c < 8; ++c) {
        float4 t = reinterpret_cast<const float4*>(p)[c];
        x[4*c+0] = t.x; x[4*c+1] = t.y; x[4*c+2] = t.z; x[4*c+3] = t.w;
    }
}

// In-place LayerNorm over 32 elements (pairwise trees for mean / mean-square)
__device__ __forceinline__ void ln_inplace(float x[DIM],
                                           const float* __restrict__ g,
                                           const float* __restrict__ bb) {
    float s[16], q[16];
    #pragma unroll
    for (int i = 0; i < 16; ++i) {
        s[i] = x[i] + x[i+16];
        q[i] = fmaf(x[i], x[i], x[i+16]*x[i+16]);
    }
    #pragma unroll
    for (int i = 0; i < 8; ++i) { s[i] += s[i+8]; q[i] += q[i+8]; }
    #pragma unroll
    for (int i = 0; i < 4; ++i) { s[i] += s[i+4]; q[i] += q[i+4]; }
    s[0] += s[2]; s[1] += s[3]; q[0] += q[2]; q[1] += q[3];
    const float mu  = (s[0] + s[1]) * (1.0f/32.0f);
    const float ms  = (q[0] + q[1]) * (1.0f/32.0f);
    const float var = ms - mu*mu;
    const float rs  = __builtin_amdgcn_rsqf(var + 1e-5f);
    #pragma unroll
    for (int d = 0; d < DIM; ++d) {
        const float t = (x[d] - mu) * rs;
        x[d] = fmaf(t, g[d], bb[d]);
    }
}

// y[c] = sum_d x[d]*W[c][d] + bias[c]  (W rows uniform -> s_loads)
__device__ __forceinline__ void gemv_reg(const float x[DIM],
                                         const float* __restrict__ W,
                                         const float* __restrict__ bias,
                                         float y[DIM]) {
    #pragma unroll
    for (int c = 0; c < DIM; ++c) {
        float acc = bias[c];
        #pragma unroll
        for (int d = 0; d < DIM; ++d) acc = fmaf(x[d], W[(c<<5)+d], acc);
        y[c] = acc;
    }
}

// Store one row to LDS with 16B-chunk rotation (bank-spread for the row-strided
// write pattern; reads are row-uniform broadcasts, rotation undone by reader).
__device__ __forceinline__ void store_row_swz(float* __restrict__ buf, int row,
                                              const float y[DIM]) {
    #pragma unroll
    for (int cc = 0; cc < 8; ++cc) {
        const int phys = (cc + row) & 7;
        float4 t;
        t.x = y[4*cc+0]; t.y = y[4*cc+1]; t.z = y[4*cc+2]; t.w = y[4*cc+3];
        *reinterpret_cast<float4*>(&buf[(row << 5) + (phys << 2)]) = t;
    }
}

__device__ __forceinline__ void epilogue_row(const float ctx_in[DIM], const float l[4],
                                             const float* __restrict__ Wo,
                                             const float* __restrict__ bo,
                                             const float* __restrict__ qres,
                                             float* __restrict__ outp) {
    float inv[4];
    #pragma unroll
    for (int h = 0; h < 4; ++h) inv[h] = __builtin_amdgcn_rcpf(l[h]);
    float ctx[DIM];
    #pragma unroll
    for (int d = 0; d < DIM; ++d) ctx[d] = ctx_in[d] * inv[d>>3];

    const float4* q4 = reinterpret_cast<const float4*>(qres);
    float4* o4 = reinterpret_cast<float4*>(outp);
    for (int cg = 0; cg < 8; ++cg) {          // rolled: uniform W index -> s_load
        float a0 = bo[cg*4+0], a1 = bo[cg*4+1], a2 = bo[cg*4+2], a3 = bo[cg*4+3];
        #pragma unroll
        for (int d = 0; d < DIM; ++d) {
            a0 = fmaf(ctx[d], Wo[((cg*4+0)<<5)+d], a0);
            a1 = fmaf(ctx[d], Wo[((cg*4+1)<<5)+d], a1);
            a2 = fmaf(ctx[d], Wo[((cg*4+2)<<5)+d], a2);
            a3 = fmaf(ctx[d], Wo[((cg*4+3)<<5)+d], a3);
        }
        const float4 qv = q4[cg];
        float4 ov;
        ov.x = a0 + qv.x; ov.y = a1 + qv.y; ov.z = a2 + qv.z; ov.w = a3 + qv.w;
        o4[cg] = ov;
    }
}

// One batch per 64-thread (single-wave) block; lane r owns q-row r (r < 50).
// LDS = K+V for ONE batch = 12.8 KB -> 12 blocks/CU (vs 3 before).
__global__ __launch_bounds__(64, 3)
void mha_fused(const float* __restrict__ Q, const float* __restrict__ K,
               const float* __restrict__ V,
               const float* __restrict__ ln_g, const float* __restrict__ ln_b,
               const float* __restrict__ Wq, const float* __restrict__ bq,
               const float* __restrict__ Wk, const float* __restrict__ bk,
               const float* __restrict__ Wv, const float* __restrict__ bv,
               const float* __restrict__ Wo, const float* __restrict__ bo,
               float* __restrict__ Out, int nbatch)
{
    __shared__ __align__(16) float sK[SEQ * DIM];
    __shared__ __align__(16) float sV[SEQ * DIM];

    const int batch = (int)blockIdx.x;
    if (batch >= nbatch) return;
    const int r   = threadIdx.x;          // lane = query row
    const bool act = (r < SEQ);
    const size_t base = (size_t)batch * (SEQ * DIM);

    float q[DIM];
    if (act) {
        const size_t off = base + (size_t)r * DIM;
        // Issue all three row loads up front: one global latency, not three.
        float xk[DIM], xv[DIM], xq[DIM];
        load_row(K + off, xk);
        load_row(V + off, xv);
        load_row(Q + off, xq);

        float y[DIM];
        ln_inplace(xk, ln_g, ln_b);
        gemv_reg(xk, Wk, bk, y);
        store_row_swz(sK, r, y);
        ln_inplace(xv, ln_g, ln_b);
        gemv_reg(xv, Wv, bv, y);
        store_row_swz(sV, r, y);
        ln_inplace(xq, ln_g, ln_b);
        gemv_reg(xq, Wq, bq, q);
        // fold 1/sqrt(8) AND log2(e): softmax exp becomes a bare v_exp_f32
        const float sc = 0.35355339059327373f * 1.4426950408889634f;
        #pragma unroll
        for (int d = 0; d < DIM; ++d) q[d] *= sc;
    }
    __syncthreads();   // single-wave block: effectively a waitcnt, near-free

    if (act) {
        float ctx[DIM];
        #pragma unroll
        for (int d = 0; d < DIM; ++d) ctx[d] = 0.0f;
        float l[4] = {0.0f, 0.0f, 0.0f, 0.0f};

        #pragma unroll 2
        for (int j = 0; j < SEQ; ++j) {
            // K row j: uniform address across lanes -> broadcast, conflict-free
            float kj[DIM];
            #pragma unroll
            for (int cc = 0; cc < 8; ++cc) {
                const int phys = (cc + j) & 7;
                const float4 tk = *reinterpret_cast<const float4*>(&sK[(j << 5) + (phys << 2)]);
                kj[4*cc+0]=tk.x; kj[4*cc+1]=tk.y; kj[4*cc+2]=tk.z; kj[4*cc+3]=tk.w;
            }
            float s[4] = {0.0f, 0.0f, 0.0f, 0.0f};
            #pragma unroll
            for (int d = 0; d < DIM; ++d) s[d>>3] = fmaf(q[d], kj[d], s[d>>3]);

            const bool um = (j <= r);         // causal mask, diagonal unmasked
            float p[4];
            #pragma unroll
            for (int h = 0; h < 4; ++h) {
                p[h] = um ? __builtin_amdgcn_exp2f(s[h]) : 0.0f;
                l[h] += p[h];
            }

            float vj[DIM];
            #pragma unroll
            for (int cc = 0; cc < 8; ++cc) {
                const int phys = (cc + j) & 7;
                const float4 tv = *reinterpret_cast<const float4*>(&sV[(j << 5) + (phys << 2)]);
                vj[4*cc+0]=tv.x; vj[4*cc+1]=tv.y; vj[4*cc+2]=tv.z; vj[4*cc+3]=tv.w;
            }
            #pragma unroll
            for (int d = 0; d < DIM; ++d) ctx[d] = fmaf(p[d>>3], vj[d], ctx[d]);
        }

        epilogue_row(ctx, l, Wo, bo, Q + base + (size_t)r * DIM,
                     Out + base + (size_t)r * DIM);
    }
}

extern "C" void kernel_launch(void* const* d_in, const int* in_sizes, int n_in,
                              void* d_out, int out_size, void* d_ws, size_t ws_size,
                              hipStream_t stream) {
    const float* Q    = (const float*)d_in[0];
    const float* K    = (const float*)d_in[1];
    const float* V    = (const float*)d_in[2];
    // d_in[3] = mask : causal triu(k=1); computed analytically, not read
    const float* ln_g = (const float*)d_in[4];
    const float* ln_b = (const float*)d_in[5];
    const float* Wq   = (const float*)d_in[6];
    const float* bq   = (const float*)d_in[7];
    const float* Wk   = (const float*)d_in[8];
    const float* bk   = (const float*)d_in[9];
    const float* Wv   = (const float*)d_in[10];
    const float* bv   = (const float*)d_in[11];
    const float* Wo   = (const float*)d_in[12];
    const float* bo   = (const float*)d_in[13];
    float* Out = (float*)d_out;

    const int nbatch = in_sizes[0] / (SEQ * DIM);   // 16384
    hipLaunchKernelGGL(mha_fused, dim3(nbatch), dim3(64), 0, stream,
                       Q, K, V, ln_g, ln_b, Wq, bq, Wk, bk, Wv, bv, Wo, bo,
                       Out, nbatch);
}